// Round 1
// baseline (227.364 us; speedup 1.0000x reference)
//
#include <hip/hip_runtime.h>

// Problem constants: B=1024, V=64, DIN=256, DOUT=256, fp32 in/out.
#define EPS 1e-5f

typedef __bf16 bf16_t;
typedef bf16_t bf16x4 __attribute__((ext_vector_type(4)));
typedef bf16_t bf16x8 __attribute__((ext_vector_type(8)));
typedef float  floatx4 __attribute__((ext_vector_type(4)));

// ---------------------------------------------------------------------------
// K0: WT[v][o][i] = (bf16)W[v][i][o]  (k-contiguous for MFMA B fragments)
//     block 256 = (v, i-chunk): v = bx>>2, i0 = (bx&3)*64
//     block 256 also does adjT[v][u] = adj[u][v]
// ---------------------------------------------------------------------------
__global__ __launch_bounds__(256) void k0_transpose(
    const float* __restrict__ W, const float* __restrict__ adj,
    bf16_t* __restrict__ WT, float* __restrict__ adjT) {
  int bx = blockIdx.x;
  int tid = threadIdx.x;
  if (bx == 256) {
    for (int idx = tid; idx < 4096; idx += 256) {
      int vv = idx >> 6, u = idx & 63;
      adjT[idx] = adj[u * 64 + vv];
    }
    return;
  }
  int v = bx >> 2, i0 = (bx & 3) * 64;
  __shared__ float t[64][129];  // +1 pad: column reads 2-way (free)
  const float* Wv = W + (size_t)v * 65536;
  bf16_t* WTv = WT + (size_t)v * 65536;
  for (int oh = 0; oh < 2; ++oh) {
    __syncthreads();
    // load 64 i-rows x 128 o, coalesced
    #pragma unroll
    for (int it = 0; it < 8; ++it) {
      int idx = it * 256 + tid;       // 2048 float4s
      int r = idx >> 5, c = idx & 31;
      float4 f = *(const float4*)(Wv + (size_t)(i0 + r) * 256 + oh * 128 + c * 4);
      t[r][c * 4 + 0] = f.x; t[r][c * 4 + 1] = f.y;
      t[r][c * 4 + 2] = f.z; t[r][c * 4 + 3] = f.w;
    }
    __syncthreads();
    // write transposed rows: o = oh*128 + rp, i = i0 + cp (contiguous in cp)
    #pragma unroll
    for (int it = 0; it < 32; ++it) {
      int idx = it * 256 + tid;       // 8192 elems
      int rp = idx >> 6, cp = idx & 63;
      WTv[(size_t)(oh * 128 + rp) * 256 + i0 + cp] = (bf16_t)t[cp][rp];
    }
  }
}

// ---------------------------------------------------------------------------
// K1: per-vertex GEMM h[b, v, o] = feat[b, v, :] @ W[v] + bias[v]
//     bf16 MFMA 16x16x32. Block tile 128(b) x 128(o), BK=32, 4 waves 2x2,
//     each wave 4x4 of 16x16 tiles. Epilogue: store h bf16 + stats atomics.
//     grid dim3(64, 2, 8): v fastest -> same-v blocks on same XCD (WT in L2).
// ---------------------------------------------------------------------------
__global__ __launch_bounds__(256) void k1_gemm(
    const float* __restrict__ feat, const bf16_t* __restrict__ WT,
    const float* __restrict__ bias, bf16_t* __restrict__ h,
    float* __restrict__ g_sum, float* __restrict__ g_sq) {
  // pad 40 (=5x16B): row stride 80B keeps ds_read_b128 16B-aligned, 2-way banks
  __shared__ __attribute__((aligned(16))) bf16_t As[128][40];
  __shared__ __attribute__((aligned(16))) bf16_t Bs[128][40];
  __shared__ float s_sum[128], s_sq[128];

  int tid = threadIdx.x;
  int lane = tid & 63, wave = tid >> 6;
  int wm = wave >> 1, wn = wave & 1;
  int r16 = lane & 15, quad = lane >> 4;
  int v = blockIdx.x, nt = blockIdx.y, bt = blockIdx.z;
  int b0 = bt * 128, n0 = nt * 128;

  if (tid < 128) { s_sum[tid] = 0.f; s_sq[tid] = 0.f; }

  floatx4 acc[4][4] = {};

  const float* featp = feat + (size_t)v * 256;
  const bf16_t* WTp = WT + (size_t)v * 65536 + (size_t)n0 * 256;

  int ar = tid >> 3, ac = tid & 7;  // A stage: row 0..31 (+i*32), float4 col
  int br = tid >> 2, bc = tid & 3;  // B stage: row 0..63 (+i*64), 8-elem chunk

  for (int ks = 0; ks < 8; ++ks) {
    int k0 = ks * 32;
    // stage A: 128 rows x 32 k, fp32 load -> bf16 cvt -> LDS
    #pragma unroll
    for (int i = 0; i < 4; ++i) {
      int row = ar + i * 32;
      float4 f = *(const float4*)(featp + (size_t)(b0 + row) * 16384 + k0 + ac * 4);
      bf16x4 pk = {(bf16_t)f.x, (bf16_t)f.y, (bf16_t)f.z, (bf16_t)f.w};
      *(bf16x4*)&As[row][ac * 4] = pk;
    }
    // stage B: 128 n-rows x 32 k, already bf16, 16B vector copies
    #pragma unroll
    for (int i = 0; i < 2; ++i) {
      int row = br + i * 64;
      uint4 w = *(const uint4*)(WTp + (size_t)row * 256 + k0 + bc * 8);
      *(uint4*)&Bs[row][bc * 8] = w;
    }
    __syncthreads();
    // fragments: a[j] = A[m=lane&15][k=quad*8+j]; b[j] = B[k=quad*8+j][n=lane&15]
    bf16x8 af[4], bfr[4];
    #pragma unroll
    for (int mi = 0; mi < 4; ++mi)
      af[mi] = *(const bf16x8*)&As[wm * 64 + mi * 16 + r16][quad * 8];
    #pragma unroll
    for (int ni = 0; ni < 4; ++ni)
      bfr[ni] = *(const bf16x8*)&Bs[wn * 64 + ni * 16 + r16][quad * 8];
    #pragma unroll
    for (int mi = 0; mi < 4; ++mi)
      #pragma unroll
      for (int ni = 0; ni < 4; ++ni)
        acc[mi][ni] = __builtin_amdgcn_mfma_f32_16x16x32_bf16(
            af[mi], bfr[ni], acc[mi][ni], 0, 0, 0);
    __syncthreads();
  }

  // epilogue: C/D layout col=lane&15, row=quad*4+reg
  float bias_r[4];
  #pragma unroll
  for (int ni = 0; ni < 4; ++ni)
    bias_r[ni] = bias[v * 256 + n0 + wn * 64 + ni * 16 + r16];

  bf16_t* hp = h + (size_t)v * 256 + n0;
  #pragma unroll
  for (int ni = 0; ni < 4; ++ni) {
    int ncol = wn * 64 + ni * 16 + r16;
    float psum = 0.f, psq = 0.f;
    #pragma unroll
    for (int mi = 0; mi < 4; ++mi) {
      #pragma unroll
      for (int r = 0; r < 4; ++r) {
        int mrow = wm * 64 + mi * 16 + quad * 4 + r;
        float val = acc[mi][ni][r] + bias_r[ni];
        bf16_t hbv = (bf16_t)val;
        hp[(size_t)(b0 + mrow) * 16384 + ncol] = hbv;
        float hf = (float)hbv;  // stats from the STORED value (self-consistent BN)
        psum += hf; psq += hf * hf;
      }
    }
    atomicAdd(&s_sum[ncol], psum);
    atomicAdd(&s_sq[ncol], psq);
  }
  __syncthreads();
  if (tid < 128) {
    atomicAdd(&g_sum[v * 256 + n0 + tid], s_sum[tid]);
    atomicAdd(&g_sq[v * 256 + n0 + tid], s_sq[tid]);
  }
}

// ---------------------------------------------------------------------------
// K2: fold BN into per-(v,o) affine: a = gamma*rsqrt(var+eps), c = beta - mean*a
// ---------------------------------------------------------------------------
__global__ __launch_bounds__(256) void k2_stats(
    const float* __restrict__ g_sum, const float* __restrict__ g_sq,
    const float* __restrict__ gamma, const float* __restrict__ beta,
    float* __restrict__ a_ws, float* __restrict__ c_ws) {
  int idx = blockIdx.x * 256 + threadIdx.x;  // 0..16383 = v*256+o
  float s = g_sum[idx], q = g_sq[idx];
  float mean = s * (1.0f / 1024.0f);
  float var = fmaxf(q * (1.0f / 1024.0f) - mean * mean, 0.f);
  float rs = rsqrtf(var + EPS);
  float a = gamma[idx] * rs;
  a_ws[idx] = a;
  c_ws[idx] = beta[idx] - mean * a;
}

// ---------------------------------------------------------------------------
// K3: out[b,u,o] = relu(sum_v adj[u,v] * (a*h+c)[b,v,o]); one block per b.
//     hbn staged in LDS (fp32 64KB); adjT via global broadcast loads (L1-hot)
//     so the LDS pipe only serves the stride-1 ds_read_b128 of hbn.
// ---------------------------------------------------------------------------
__global__ __launch_bounds__(256) void k3_mix(
    const bf16_t* __restrict__ h, const float* __restrict__ adjT,
    const float* __restrict__ a_ws, const float* __restrict__ c_ws,
    float* __restrict__ out) {
  __shared__ float hs[64][256];
  int tid = threadIdx.x;
  int b = blockIdx.x;
  const bf16_t* hb = h + (size_t)b * 16384;
  // stage + normalize: hs[v][o] = a*h + c   (linear idx = v*256+o)
  #pragma unroll
  for (int i = 0; i < 8; ++i) {
    int vidx = i * 256 + tid;  // 8-elem chunk index, lane-contiguous 16B
    bf16x8 hv = *(const bf16x8*)(hb + (size_t)vidx * 8);
    const float* ap = a_ws + (size_t)vidx * 8;
    const float* cp = c_ws + (size_t)vidx * 8;
    float4 a0 = *(const float4*)ap, a1 = *(const float4*)(ap + 4);
    float4 c0 = *(const float4*)cp, c1 = *(const float4*)(cp + 4);
    float* dst = &hs[0][0] + (size_t)vidx * 8;
    float4 d0 = {fmaf((float)hv[0], a0.x, c0.x), fmaf((float)hv[1], a0.y, c0.y),
                 fmaf((float)hv[2], a0.z, c0.z), fmaf((float)hv[3], a0.w, c0.w)};
    float4 d1 = {fmaf((float)hv[4], a1.x, c1.x), fmaf((float)hv[5], a1.y, c1.y),
                 fmaf((float)hv[6], a1.z, c1.z), fmaf((float)hv[7], a1.w, c1.w)};
    *(float4*)dst = d0;
    *(float4*)(dst + 4) = d1;
  }
  __syncthreads();

  int o4 = tid & 63;            // float4 column chunk (o = o4*4)
  int u0 = (tid >> 6) * 16;     // 16 u-rows per wave
  floatx4 acc[16] = {};
  const float* hcol = &hs[0][o4 * 4];
  #pragma unroll 4
  for (int v = 0; v < 64; ++v) {
    floatx4 hv = *(const floatx4*)(hcol + v * 256);
    const float* ajp = adjT + v * 64 + u0;  // wave-uniform -> broadcast, L1-hot
    #pragma unroll
    for (int i = 0; i < 4; ++i) {
      float4 aj = *(const float4*)(ajp + i * 4);
      acc[i * 4 + 0] += aj.x * hv;
      acc[i * 4 + 1] += aj.y * hv;
      acc[i * 4 + 2] += aj.z * hv;
      acc[i * 4 + 3] += aj.w * hv;
    }
  }
  float* op = out + (size_t)b * 16384 + o4 * 4;
  #pragma unroll
  for (int i = 0; i < 16; ++i) {
    floatx4 r = acc[i];
    float4 st = {fmaxf(r[0], 0.f), fmaxf(r[1], 0.f),
                 fmaxf(r[2], 0.f), fmaxf(r[3], 0.f)};
    *(float4*)(op + (size_t)(u0 + i) * 256) = st;
  }
}

// ---------------------------------------------------------------------------
extern "C" void kernel_launch(void* const* d_in, const int* in_sizes, int n_in,
                              void* d_out, int out_size, void* d_ws, size_t ws_size,
                              hipStream_t stream) {
  const float* feat  = (const float*)d_in[0];  // [1024, 64, 256]
  const float* adj   = (const float*)d_in[1];  // [64, 64]
  const float* W     = (const float*)d_in[2];  // [64, 256, 256]
  const float* bias  = (const float*)d_in[3];  // [64, 256]
  const float* gamma = (const float*)d_in[4];  // [64, 256]
  const float* beta  = (const float*)d_in[5];  // [64, 256]
  float* out = (float*)d_out;                  // [1024, 64, 256]

  char* ws = (char*)d_ws;
  // ws layout (needs ~40.3 MB):
  bf16_t* WT   = (bf16_t*)ws;                               //  8 MB  [V][O][I] bf16
  bf16_t* hbuf = (bf16_t*)(ws + (size_t)(8u << 20));        // 32 MB  [B][V][O] bf16
  char* tail   = ws + (size_t)(40u << 20);
  float* g_sum = (float*)tail;                              // 64 KB
  float* g_sq  = (float*)(tail + 65536);                    // 64 KB
  float* a_ws  = (float*)(tail + 2 * 65536);                // 64 KB
  float* c_ws  = (float*)(tail + 3 * 65536);                // 64 KB
  float* adjT  = (float*)(tail + 4 * 65536);                // 16 KB

  hipMemsetAsync(g_sum, 0, 2 * 65536, stream);  // stats accumulators -> 0

  k0_transpose<<<257, 256, 0, stream>>>(W, adj, WT, adjT);
  k1_gemm<<<dim3(64, 2, 8), 256, 0, stream>>>(feat, WT, bias, hbuf, g_sum, g_sq);
  k2_stats<<<64, 256, 0, stream>>>(g_sum, g_sq, gamma, beta, a_ws, c_ws);
  k3_mix<<<1024, 256, 0, stream>>>(hbuf, adjT, a_ws, c_ws, out);
}

// Round 2
// 205.534 us; speedup vs baseline: 1.1062x; 1.1062x over previous
//
#include <hip/hip_runtime.h>

// Problem constants: B=1024, V=64, DIN=256, DOUT=256, fp32 in/out.
#define EPS 1e-5f

typedef __bf16 bf16_t;
typedef bf16_t bf16x4 __attribute__((ext_vector_type(4)));
typedef bf16_t bf16x8 __attribute__((ext_vector_type(8)));
typedef float  floatx4 __attribute__((ext_vector_type(4)));

// ---------------------------------------------------------------------------
// K0: WT[v][o][i] = (bf16)W[v][i][o]  (k-contiguous for MFMA B fragments)
//     + adjT[v][u] = adj[u][v]. Vectorized bf16x4 stores (round-1 used 2B
//     scalar stores).
// ---------------------------------------------------------------------------
__global__ __launch_bounds__(256) void k0_transpose(
    const float* __restrict__ W, const float* __restrict__ adj,
    bf16_t* __restrict__ WT, float* __restrict__ adjT) {
  int bx = blockIdx.x;
  int tid = threadIdx.x;
  if (bx == 256) {
    for (int idx = tid; idx < 4096; idx += 256) {
      int vv = idx >> 6, u = idx & 63;
      adjT[idx] = adj[u * 64 + vv];
    }
    return;
  }
  int v = bx >> 2, i0 = (bx & 3) * 64;
  __shared__ float t[64][129];  // col reads: bank (c+r)%32 -> 2-way, free
  const float* Wv = W + (size_t)v * 65536;
  bf16_t* WTv = WT + (size_t)v * 65536;
  for (int oh = 0; oh < 2; ++oh) {
    __syncthreads();
    // load 64 i-rows x 128 o, coalesced float4
    #pragma unroll
    for (int it = 0; it < 8; ++it) {
      int idx = it * 256 + tid;  // 2048 float4s
      int r = idx >> 5, c = idx & 31;
      float4 f = *(const float4*)(Wv + (size_t)(i0 + r) * 256 + oh * 128 + c * 4);
      t[r][c * 4 + 0] = f.x; t[r][c * 4 + 1] = f.y;
      t[r][c * 4 + 2] = f.z; t[r][c * 4 + 3] = f.w;
    }
    __syncthreads();
    // write transposed as bf16x4: o = oh*128 + rp, i = i0 + c4*4 + k
    #pragma unroll
    for (int it = 0; it < 8; ++it) {
      int idx = it * 256 + tid;  // 2048 chunks
      int rp = idx >> 4, c4 = idx & 15;
      bf16x4 pk = {(bf16_t)t[c4 * 4 + 0][rp], (bf16_t)t[c4 * 4 + 1][rp],
                   (bf16_t)t[c4 * 4 + 2][rp], (bf16_t)t[c4 * 4 + 3][rp]};
      *(bf16x4*)(WTv + (size_t)(oh * 128 + rp) * 256 + i0 + c4 * 4) = pk;
    }
  }
}

// ---------------------------------------------------------------------------
// K1: per-vertex GEMM h[b,v,o] = feat[b,v,:] @ W[v] + bias[v], bf16 MFMA.
//     BARRIER-FREE k-loop: fragments loaded straight from global (B from WT
//     16B k-contiguous, A from fp32 feat + in-register cvt), B prefetched one
//     k-step ahead in registers. LDS only for epilogue transpose (coalesced h
//     stores) + stats. Tile 128(b)x128(o), 4 waves 2x2, 4x4 16x16 frags each.
//     grid dim3(64,2,8): v fastest, same-v blocks same XCD (WT L2-hot).
// ---------------------------------------------------------------------------
__global__ __launch_bounds__(256, 3) void k1_gemm(
    const float* __restrict__ feat, const bf16_t* __restrict__ WT,
    const float* __restrict__ bias, bf16_t* __restrict__ h,
    float* __restrict__ g_sum, float* __restrict__ g_sq) {
  __shared__ __attribute__((aligned(16))) bf16_t Cs[128][136];  // 272B row: 16B-aligned
  __shared__ float s_sum[128], s_sq[128];

  int tid = threadIdx.x;
  int lane = tid & 63, wave = tid >> 6;
  int wm = wave >> 1, wn = wave & 1;
  int r16 = lane & 15, quad = lane >> 4;
  int v = blockIdx.x, n0 = blockIdx.y * 128, b0 = blockIdx.z * 128;

  if (tid < 128) { s_sum[tid] = 0.f; s_sq[tid] = 0.f; }

  floatx4 acc[4][4] = {};

  // fragment base pointers (per-step offsets become immediate offsets)
  const float* ap[4];
  const bf16_t* bp[4];
  #pragma unroll
  for (int mi = 0; mi < 4; ++mi)
    ap[mi] = feat + (size_t)(b0 + wm * 64 + mi * 16 + r16) * 16384 + v * 256 + quad * 8;
  #pragma unroll
  for (int ni = 0; ni < 4; ++ni)
    bp[ni] = WT + (size_t)v * 65536 + (size_t)(n0 + wn * 64 + ni * 16 + r16) * 256 + quad * 8;

  bf16x8 bfr[4], nb[4];
  #pragma unroll
  for (int ni = 0; ni < 4; ++ni) bfr[ni] = *(const bf16x8*)bp[ni];

  #pragma unroll
  for (int ks = 0; ks < 8; ++ks) {
    // A for current step (fp32, 2x16B per frag) — latency covered by resident
    // waves round-robin (no barrier anywhere in this loop)
    float4 t0[4], t1[4];
    #pragma unroll
    for (int mi = 0; mi < 4; ++mi) {
      t0[mi] = *(const float4*)(ap[mi] + ks * 32);
      t1[mi] = *(const float4*)(ap[mi] + ks * 32 + 4);
    }
    // B prefetch for next step
    if (ks < 7) {
      #pragma unroll
      for (int ni = 0; ni < 4; ++ni)
        nb[ni] = *(const bf16x8*)(bp[ni] + (ks + 1) * 32);
    }
    #pragma unroll
    for (int mi = 0; mi < 4; ++mi) {
      bf16x8 af = {(bf16_t)t0[mi].x, (bf16_t)t0[mi].y, (bf16_t)t0[mi].z, (bf16_t)t0[mi].w,
                   (bf16_t)t1[mi].x, (bf16_t)t1[mi].y, (bf16_t)t1[mi].z, (bf16_t)t1[mi].w};
      #pragma unroll
      for (int ni = 0; ni < 4; ++ni)
        acc[mi][ni] = __builtin_amdgcn_mfma_f32_16x16x32_bf16(
            af, bfr[ni], acc[mi][ni], 0, 0, 0);
    }
    if (ks < 7) {
      #pragma unroll
      for (int ni = 0; ni < 4; ++ni) bfr[ni] = nb[ni];
    }
  }

  __syncthreads();  // s_sum/s_sq zeros visible before atomics; Cs free to use

  // epilogue: C/D layout col=lane&15, row=quad*4+reg. Stats from the STORED
  // bf16 value (self-consistent BN). Stage C into LDS for coalesced h writes.
  float bias_r[4];
  #pragma unroll
  for (int ni = 0; ni < 4; ++ni)
    bias_r[ni] = bias[v * 256 + n0 + wn * 64 + ni * 16 + r16];

  #pragma unroll
  for (int ni = 0; ni < 4; ++ni) {
    int ncol = wn * 64 + ni * 16 + r16;
    float psum = 0.f, psq = 0.f;
    #pragma unroll
    for (int mi = 0; mi < 4; ++mi) {
      #pragma unroll
      for (int r = 0; r < 4; ++r) {
        int mrow = wm * 64 + mi * 16 + quad * 4 + r;
        float val = acc[mi][ni][r] + bias_r[ni];
        bf16_t hbv = (bf16_t)val;
        Cs[mrow][ncol] = hbv;
        float hf = (float)hbv;
        psum += hf; psq += hf * hf;
      }
    }
    atomicAdd(&s_sum[ncol], psum);
    atomicAdd(&s_sq[ncol], psq);
  }
  __syncthreads();

  // coalesced h write: 16 lanes x 16B = 256B per b-row, 4 rows per wave-instr
  bf16_t* hp = h + (size_t)v * 256 + n0;
  int col0 = (tid & 15) * 8;
  #pragma unroll
  for (int it = 0; it < 8; ++it) {
    int row = it * 16 + (tid >> 4);
    *(bf16x8*)(hp + (size_t)(b0 + row) * 16384 + col0) = *(const bf16x8*)&Cs[row][col0];
  }
  if (tid < 128) {
    atomicAdd(&g_sum[v * 256 + n0 + tid], s_sum[tid]);
    atomicAdd(&g_sq[v * 256 + n0 + tid], s_sq[tid]);
  }
}

// ---------------------------------------------------------------------------
// K2: fold BN into per-(v,o) affine: a = gamma*rsqrt(var+eps), c = beta - mean*a
// ---------------------------------------------------------------------------
__global__ __launch_bounds__(256) void k2_stats(
    const float* __restrict__ g_sum, const float* __restrict__ g_sq,
    const float* __restrict__ gamma, const float* __restrict__ beta,
    float* __restrict__ a_ws, float* __restrict__ c_ws) {
  int idx = blockIdx.x * 256 + threadIdx.x;  // v*256+o
  float s = g_sum[idx], q = g_sq[idx];
  float mean = s * (1.0f / 1024.0f);
  float var = fmaxf(q * (1.0f / 1024.0f) - mean * mean, 0.f);
  float rs = rsqrtf(var + EPS);
  float a = gamma[idx] * rs;
  a_ws[idx] = a;
  c_ws[idx] = beta[idx] - mean * a;
}

// ---------------------------------------------------------------------------
// K3: out[b,u,o] = relu(sum_v adj[u,v] * (a*h+c)[b,v,o]); one block per b.
//     hbn staged bf16 in LDS (33KB) + adj staged in LDS (16KB, wave-uniform
//     broadcast reads = conflict-free) -> 3 blocks/CU, no global loads in the
//     v-loop. VALU floor 13.7us, memory floor 15.2us.
// ---------------------------------------------------------------------------
__global__ __launch_bounds__(256) void k3_mix(
    const bf16_t* __restrict__ h, const float* __restrict__ adjT,
    const float* __restrict__ a_ws, const float* __restrict__ c_ws,
    float* __restrict__ out) {
  __shared__ __attribute__((aligned(16))) bf16_t hs[64][264];  // 528B row, 16B-aligned
  __shared__ float adjs[4096];
  int tid = threadIdx.x;
  int b = blockIdx.x;
  // stage adj (16KB, from L2/L3)
  #pragma unroll
  for (int i = 0; i < 4; ++i) {
    int idx = i * 256 + tid;
    *(float4*)&adjs[idx * 4] = *(const float4*)(adjT + idx * 4);
  }
  // stage + normalize: hs[v][o] = bf16(a*h + c)
  const bf16_t* hb = h + (size_t)b * 16384;
  #pragma unroll
  for (int i = 0; i < 8; ++i) {
    int vidx = i * 256 + tid;  // 8-elem chunk index
    bf16x8 hv = *(const bf16x8*)(hb + (size_t)vidx * 8);
    const float* ap = a_ws + (size_t)vidx * 8;
    const float* cp = c_ws + (size_t)vidx * 8;
    float4 a0 = *(const float4*)ap, a1 = *(const float4*)(ap + 4);
    float4 c0 = *(const float4*)cp, c1 = *(const float4*)(cp + 4);
    bf16x8 d;
    d[0] = (bf16_t)fmaf((float)hv[0], a0.x, c0.x);
    d[1] = (bf16_t)fmaf((float)hv[1], a0.y, c0.y);
    d[2] = (bf16_t)fmaf((float)hv[2], a0.z, c0.z);
    d[3] = (bf16_t)fmaf((float)hv[3], a0.w, c0.w);
    d[4] = (bf16_t)fmaf((float)hv[4], a1.x, c1.x);
    d[5] = (bf16_t)fmaf((float)hv[5], a1.y, c1.y);
    d[6] = (bf16_t)fmaf((float)hv[6], a1.z, c1.z);
    d[7] = (bf16_t)fmaf((float)hv[7], a1.w, c1.w);
    *(bf16x8*)&hs[vidx >> 5][(vidx & 31) * 8] = d;
  }
  __syncthreads();

  int o4 = tid & 63;          // o = o4*4
  int u0 = (tid >> 6) * 16;   // 16 u-rows per wave
  floatx4 acc[16] = {};
  const float* adjp = adjs + u0;
  #pragma unroll 8
  for (int v = 0; v < 64; ++v) {
    bf16x4 h4 = *(const bf16x4*)&hs[v][o4 * 4];  // 64 lanes x 8B contiguous
    floatx4 hv = {(float)h4[0], (float)h4[1], (float)h4[2], (float)h4[3]};
    const float* aj = adjp + v * 64;  // wave-uniform -> LDS broadcast
    #pragma unroll
    for (int i = 0; i < 4; ++i) {
      float4 a4 = *(const float4*)(aj + i * 4);
      acc[i * 4 + 0] += a4.x * hv;
      acc[i * 4 + 1] += a4.y * hv;
      acc[i * 4 + 2] += a4.z * hv;
      acc[i * 4 + 3] += a4.w * hv;
    }
  }
  float* op = out + (size_t)b * 16384 + o4 * 4;
  #pragma unroll
  for (int i = 0; i < 16; ++i) {
    floatx4 r = acc[i];
    float4 st = {fmaxf(r[0], 0.f), fmaxf(r[1], 0.f),
                 fmaxf(r[2], 0.f), fmaxf(r[3], 0.f)};
    *(float4*)(op + (size_t)(u0 + i) * 256) = st;
  }
}

// ---------------------------------------------------------------------------
extern "C" void kernel_launch(void* const* d_in, const int* in_sizes, int n_in,
                              void* d_out, int out_size, void* d_ws, size_t ws_size,
                              hipStream_t stream) {
  const float* feat  = (const float*)d_in[0];  // [1024, 64, 256]
  const float* adj   = (const float*)d_in[1];  // [64, 64]
  const float* W     = (const float*)d_in[2];  // [64, 256, 256]
  const float* bias  = (const float*)d_in[3];  // [64, 256]
  const float* gamma = (const float*)d_in[4];  // [64, 256]
  const float* beta  = (const float*)d_in[5];  // [64, 256]
  float* out = (float*)d_out;                  // [1024, 64, 256]

  char* ws = (char*)d_ws;
  bf16_t* WT   = (bf16_t*)ws;                               //  8 MB  [V][O][I] bf16
  bf16_t* hbuf = (bf16_t*)(ws + (size_t)(8u << 20));        // 32 MB  [B][V][O] bf16
  char* tail   = ws + (size_t)(40u << 20);
  float* g_sum = (float*)tail;                              // 64 KB
  float* g_sq  = (float*)(tail + 65536);                    // 64 KB
  float* a_ws  = (float*)(tail + 2 * 65536);                // 64 KB
  float* c_ws  = (float*)(tail + 3 * 65536);                // 64 KB
  float* adjT  = (float*)(tail + 4 * 65536);                // 16 KB

  hipMemsetAsync(g_sum, 0, 2 * 65536, stream);  // stats accumulators -> 0

  k0_transpose<<<257, 256, 0, stream>>>(W, adj, WT, adjT);
  k1_gemm<<<dim3(64, 2, 8), 256, 0, stream>>>(feat, WT, bias, hbuf, g_sum, g_sq);
  k2_stats<<<64, 256, 0, stream>>>(g_sum, g_sq, gamma, beta, a_ws, c_ws);
  k3_mix<<<1024, 256, 0, stream>>>(hbuf, adjT, a_ws, c_ws, out);
}

// Round 3
// 188.949 us; speedup vs baseline: 1.2033x; 1.0878x over previous
//
#include <hip/hip_runtime.h>

// Problem constants: B=1024, V=64, DIN=256, DOUT=256, fp32 in/out.
#define EPS 1e-5f

typedef __bf16 bf16_t;
typedef bf16_t bf16x4 __attribute__((ext_vector_type(4)));
typedef bf16_t bf16x8 __attribute__((ext_vector_type(8)));
typedef float  floatx4 __attribute__((ext_vector_type(4)));

// Fragment-pack layouts (verified per-lane mapping from r1/r2 passing kernels):
//   A-frag chunk (mt, ks, lane): element A[m = mt*16 + (lane&15)][k = ks*32 + (lane>>4)*8 + j]
//   B-frag chunk (nt, ks, lane): element B[k = ks*32 + (lane>>4)*8 + j][n = nt*16 + (lane&15)]
//   C/D: col = lane&15, row = (lane>>4)*4 + reg

// ---------------------------------------------------------------------------
// K0a: Bp[v][nt16][ks8][lane][8] = bf16(W[v][k][n])  +  adjB = bf16(adj)
//      grid 513: bx<512 -> (v = bx>>3, ks = bx&7); bx==512 -> adj cast.
// ---------------------------------------------------------------------------
__global__ __launch_bounds__(256) void k0a_packW(
    const float* __restrict__ W, const float* __restrict__ adj,
    bf16_t* __restrict__ Bp, bf16_t* __restrict__ adjB) {
  int bx = blockIdx.x, tid = threadIdx.x;
  if (bx == 512) {  // adjB[u*64+v] = bf16(adj[u*64+v])  (no transpose)
    int base = tid * 16;
    #pragma unroll
    for (int half = 0; half < 2; ++half) {
      float4 f0 = *(const float4*)(adj + base + half * 8);
      float4 f1 = *(const float4*)(adj + base + half * 8 + 4);
      bf16x8 d = {(bf16_t)f0.x, (bf16_t)f0.y, (bf16_t)f0.z, (bf16_t)f0.w,
                  (bf16_t)f1.x, (bf16_t)f1.y, (bf16_t)f1.z, (bf16_t)f1.w};
      *(bf16x8*)(adjB + base + half * 8) = d;
    }
    return;
  }
  int v = bx >> 3, ks = bx & 7, k0 = ks * 32;
  __shared__ __attribute__((aligned(16))) float Ls[32][260];  // 1040B rows: 16B-aligned
  const float* Wv = W + (size_t)v * 65536;
  // stage W[v][k0..k0+32][0..256] coalesced
  #pragma unroll
  for (int it = 0; it < 8; ++it) {
    int idx = it * 256 + tid;            // 2048 float4
    int row = idx >> 6, c4 = idx & 63;
    *(float4*)&Ls[row][c4 * 4] = *(const float4*)(Wv + (size_t)(k0 + row) * 256 + c4 * 4);
  }
  __syncthreads();
  // gather fragments: chunk cc -> (nt = cc>>6, lane = cc&63)
  #pragma unroll
  for (int it = 0; it < 4; ++it) {
    int cc = it * 256 + tid;
    int nt = cc >> 6, lanec = cc & 63;
    int n = nt * 16 + (lanec & 15), kq = (lanec >> 4) * 8;
    bf16x8 d;
    #pragma unroll
    for (int j = 0; j < 8; ++j) d[j] = (bf16_t)Ls[kq + j][n];
    *(bf16x8*)(Bp + ((size_t)(v * 16 + nt) * 8 + ks) * 512 + lanec * 8) = d;
  }
}

// ---------------------------------------------------------------------------
// K0b: Ap[v][mt64][ks8][lane][8] = bf16(feat[b = mt*16+(lane&15)][v][k])
//      grid (v=64, bg=16, kh=2): block stages feat[bg*64..+64][v][kh*128..+128]
// ---------------------------------------------------------------------------
__global__ __launch_bounds__(256) void k0b_packA(
    const float* __restrict__ feat, bf16_t* __restrict__ Ap) {
  __shared__ __attribute__((aligned(16))) float Ls[64][132];  // 528B rows: 16B-aligned
  int tid = threadIdx.x;
  int v = blockIdx.x, bg = blockIdx.y, kh = blockIdx.z;
  const float* fp = feat + (size_t)(bg * 64) * 16384 + v * 256 + kh * 128;
  // stage 64 b-rows x 128 k, coalesced float4 (512B runs per row)
  #pragma unroll
  for (int it = 0; it < 8; ++it) {
    int idx = it * 256 + tid;            // 2048 float4
    int row = idx >> 5, c4 = idx & 31;
    *(float4*)&Ls[row][c4 * 4] = *(const float4*)(fp + (size_t)row * 16384 + c4 * 4);
  }
  __syncthreads();
  // emit fragment chunks: cc -> (mt_l = cc>>8, ks_l = (cc>>6)&3, lane = cc&63)
  #pragma unroll
  for (int it = 0; it < 4; ++it) {
    int cc = it * 256 + tid;
    int mt_l = cc >> 8, ks_l = (cc >> 6) & 3, lanec = cc & 63;
    int m_l = mt_l * 16 + (lanec & 15);
    int k_l = ks_l * 32 + (lanec >> 4) * 8;
    float4 f0 = *(const float4*)&Ls[m_l][k_l];
    float4 f1 = *(const float4*)&Ls[m_l][k_l + 4];
    bf16x8 d = {(bf16_t)f0.x, (bf16_t)f0.y, (bf16_t)f0.z, (bf16_t)f0.w,
                (bf16_t)f1.x, (bf16_t)f1.y, (bf16_t)f1.z, (bf16_t)f1.w};
    int mt = bg * 4 + mt_l, ks = kh * 4 + ks_l;
    *(bf16x8*)(Ap + ((size_t)(v * 64 + mt) * 8 + ks) * 512 + lanec * 8) = d;
  }
}

// ---------------------------------------------------------------------------
// K1: h[b,v,o] = feat[b,v,:] @ W[v] + bias[v].  Both operands fragment-packed
//     -> every load is 16B/lane COALESCED, zero LDS / barriers in the k-loop.
//     Tile 128(b)x128(o), 4 waves 2x2, 4x4 16x16 frags, K=256 (8 ksteps).
//     Epilogue (r2-verified): bias, bf16 h store via LDS, per-(v,o) stats.
// ---------------------------------------------------------------------------
__global__ __launch_bounds__(256, 3) void k1_gemm(
    const bf16_t* __restrict__ Ap, const bf16_t* __restrict__ Bp,
    const float* __restrict__ bias, bf16_t* __restrict__ h,
    float* __restrict__ g_sum, float* __restrict__ g_sq) {
  __shared__ __attribute__((aligned(16))) bf16_t Cs[128][136];
  __shared__ float s_sum[128], s_sq[128];

  int tid = threadIdx.x;
  int lane = tid & 63, wave = tid >> 6;
  int wm = wave >> 1, wn = wave & 1;
  int r16 = lane & 15, quad = lane >> 4;
  int v = blockIdx.x, n0 = blockIdx.y * 128, b0 = blockIdx.z * 128;

  if (tid < 128) { s_sum[tid] = 0.f; s_sq[tid] = 0.f; }

  floatx4 acc[4][4] = {};

  const bf16_t* apb[4];
  const bf16_t* bpb[4];
  #pragma unroll
  for (int mi = 0; mi < 4; ++mi) {
    int mt = blockIdx.z * 8 + wm * 4 + mi;
    apb[mi] = Ap + ((size_t)(v * 64 + mt) * 8) * 512 + lane * 8;
  }
  #pragma unroll
  for (int ni = 0; ni < 4; ++ni) {
    int nt = blockIdx.y * 8 + wn * 4 + ni;
    bpb[ni] = Bp + ((size_t)(v * 16 + nt) * 8) * 512 + lane * 8;
  }

  bf16x8 ac[4], bc[4], an[4], bn[4];
  #pragma unroll
  for (int mi = 0; mi < 4; ++mi) ac[mi] = *(const bf16x8*)apb[mi];
  #pragma unroll
  for (int ni = 0; ni < 4; ++ni) bc[ni] = *(const bf16x8*)bpb[ni];

  #pragma unroll
  for (int ks = 0; ks < 8; ++ks) {
    if (ks < 7) {
      #pragma unroll
      for (int mi = 0; mi < 4; ++mi) an[mi] = *(const bf16x8*)(apb[mi] + (ks + 1) * 512);
      #pragma unroll
      for (int ni = 0; ni < 4; ++ni) bn[ni] = *(const bf16x8*)(bpb[ni] + (ks + 1) * 512);
    }
    #pragma unroll
    for (int mi = 0; mi < 4; ++mi)
      #pragma unroll
      for (int ni = 0; ni < 4; ++ni)
        acc[mi][ni] = __builtin_amdgcn_mfma_f32_16x16x32_bf16(
            ac[mi], bc[ni], acc[mi][ni], 0, 0, 0);
    if (ks < 7) {
      #pragma unroll
      for (int mi = 0; mi < 4; ++mi) ac[mi] = an[mi];
      #pragma unroll
      for (int ni = 0; ni < 4; ++ni) bc[ni] = bn[ni];
    }
  }

  __syncthreads();  // s_sum/s_sq zeros visible; Cs ready for use

  float bias_r[4];
  #pragma unroll
  for (int ni = 0; ni < 4; ++ni)
    bias_r[ni] = bias[v * 256 + n0 + wn * 64 + ni * 16 + r16];

  #pragma unroll
  for (int ni = 0; ni < 4; ++ni) {
    int ncol = wn * 64 + ni * 16 + r16;
    float psum = 0.f, psq = 0.f;
    #pragma unroll
    for (int mi = 0; mi < 4; ++mi) {
      #pragma unroll
      for (int r = 0; r < 4; ++r) {
        int mrow = wm * 64 + mi * 16 + quad * 4 + r;
        float val = acc[mi][ni][r] + bias_r[ni];
        bf16_t hbv = (bf16_t)val;
        Cs[mrow][ncol] = hbv;
        float hf = (float)hbv;  // stats from STORED value (self-consistent BN)
        psum += hf; psq += hf * hf;
      }
    }
    atomicAdd(&s_sum[ncol], psum);
    atomicAdd(&s_sq[ncol], psq);
  }
  __syncthreads();

  bf16_t* hp = h + (size_t)v * 256 + n0;
  int col0 = (tid & 15) * 8;
  #pragma unroll
  for (int it = 0; it < 8; ++it) {
    int row = it * 16 + (tid >> 4);
    *(bf16x8*)(hp + (size_t)(b0 + row) * 16384 + col0) = *(const bf16x8*)&Cs[row][col0];
  }
  if (tid < 128) {
    atomicAdd(&g_sum[v * 256 + n0 + tid], s_sum[tid]);
    atomicAdd(&g_sq[v * 256 + n0 + tid], s_sq[tid]);
  }
}

// ---------------------------------------------------------------------------
// K2: fold BN into per-(v,o) affine: a = gamma*rsqrt(var+eps), c = beta - mean*a
// ---------------------------------------------------------------------------
__global__ __launch_bounds__(256) void k2_stats(
    const float* __restrict__ g_sum, const float* __restrict__ g_sq,
    const float* __restrict__ gamma, const float* __restrict__ beta,
    float* __restrict__ a_ws, float* __restrict__ c_ws) {
  int idx = blockIdx.x * 256 + threadIdx.x;
  float s = g_sum[idx], q = g_sq[idx];
  float mean = s * (1.0f / 1024.0f);
  float var = fmaxf(q * (1.0f / 1024.0f) - mean * mean, 0.f);
  float rs = rsqrtf(var + EPS);
  float a = gamma[idx] * rs;
  a_ws[idx] = a;
  c_ws[idx] = beta[idx] - mean * a;
}

// ---------------------------------------------------------------------------
// K4: out[b,u,o] = relu(sum_v adj[u,v] * (a*h+c)[b,v,o]) via bf16 MFMA.
//     One block per b. Stage hbn transposed into LDS as hsT[o][v'] (stride 66
//     elems, v rotated by (o&56) -> paired-v ds_write_b32, ~4-way). B-frags
//     read as 4x ds_read_b32; A-frags (adjB) from global, L1-hot broadcast.
//     C/D: u = mi*16+quad*4+r, o = (w*4+ni)*16+r16.
// ---------------------------------------------------------------------------
__global__ __launch_bounds__(256) void k4_mix(
    const bf16_t* __restrict__ h, const bf16_t* __restrict__ adjB,
    const float* __restrict__ a_ws, const float* __restrict__ c_ws,
    float* __restrict__ out) {
  __shared__ unsigned int hsT[256 * 33];  // 256 o-rows x 66 bf16 (33 words)
  int tid = threadIdx.x;
  int lane = tid & 63, w = tid >> 6;
  int r16 = lane & 15, quad = lane >> 4;
  int b = blockIdx.x;
  const bf16_t* hb = h + (size_t)b * 16384;

  // A-fragments (adjB 8KB, L1-hot): frag (mi, ks): u=mi*16+r16, k=ks*32+quad*8
  bf16x8 afr[4][2];
  #pragma unroll
  for (int mi = 0; mi < 4; ++mi)
    #pragma unroll
    for (int ks = 0; ks < 2; ++ks)
      afr[mi][ks] = *(const bf16x8*)(adjB + (mi * 16 + r16) * 64 + ks * 32 + quad * 8);

  // stage: iter i: idx2 = i*256+tid -> (o8 = (idx2&31)*8, vpair = idx2>>5)
  #pragma unroll
  for (int i = 0; i < 4; ++i) {
    int idx2 = i * 256 + tid;
    int o8 = (idx2 & 31) * 8;
    int v0 = (idx2 >> 5) * 2;
    bf16x8 h0 = *(const bf16x8*)(hb + (size_t)v0 * 256 + o8);
    bf16x8 h1 = *(const bf16x8*)(hb + (size_t)(v0 + 1) * 256 + o8);
    const float* a0p = a_ws + v0 * 256 + o8;
    const float* c0p = c_ws + v0 * 256 + o8;
    float4 a00 = *(const float4*)a0p, a01 = *(const float4*)(a0p + 4);
    float4 a10 = *(const float4*)(a0p + 256), a11 = *(const float4*)(a0p + 260);
    float4 c00 = *(const float4*)c0p, c01 = *(const float4*)(c0p + 4);
    float4 c10 = *(const float4*)(c0p + 256), c11 = *(const float4*)(c0p + 260);
    float av0[8] = {a00.x, a00.y, a00.z, a00.w, a01.x, a01.y, a01.z, a01.w};
    float cv0[8] = {c00.x, c00.y, c00.z, c00.w, c01.x, c01.y, c01.z, c01.w};
    float av1[8] = {a10.x, a10.y, a10.z, a10.w, a11.x, a11.y, a11.z, a11.w};
    float cv1[8] = {c10.x, c10.y, c10.z, c10.w, c11.x, c11.y, c11.z, c11.w};
    #pragma unroll
    for (int j = 0; j < 8; ++j) {
      int o = o8 + j;
      unsigned short lo, hi;
      bf16_t d0 = (bf16_t)fmaf((float)h0[j], av0[j], cv0[j]);
      bf16_t d1 = (bf16_t)fmaf((float)h1[j], av1[j], cv1[j]);
      __builtin_memcpy(&lo, &d0, 2);
      __builtin_memcpy(&hi, &d1, 2);
      int vr = (v0 + (o & 56)) & 63;           // rotate v by (o&56): keeps 8-runs intact
      hsT[o * 33 + (vr >> 1)] = (unsigned int)lo | ((unsigned int)hi << 16);
    }
  }
  __syncthreads();

  // mix: wave w -> nt = w*4..w*4+4 (o-range 64), all 4 m-tiles, 2 ksteps
  floatx4 acc[4][4] = {};
  #pragma unroll
  for (int ks = 0; ks < 2; ++ks) {
    bf16x8 bfr[4];
    #pragma unroll
    for (int ni = 0; ni < 4; ++ni) {
      int o = (w * 4 + ni) * 16 + r16;
      int vbase = ks * 32 + quad * 8;
      int vr = (vbase + (o & 56)) & 63;
      const unsigned int* src = &hsT[o * 33 + (vr >> 1)];
      unsigned int u0 = src[0], u1 = src[1], u2 = src[2], u3 = src[3];
      unsigned int tmp[4] = {u0, u1, u2, u3};
      __builtin_memcpy(&bfr[ni], tmp, 16);
    }
    #pragma unroll
    for (int mi = 0; mi < 4; ++mi)
      #pragma unroll
      for (int ni = 0; ni < 4; ++ni)
        acc[mi][ni] = __builtin_amdgcn_mfma_f32_16x16x32_bf16(
            afr[mi][ks], bfr[ni], acc[mi][ni], 0, 0, 0);
  }

  float* ob = out + (size_t)b * 16384;
  #pragma unroll
  for (int mi = 0; mi < 4; ++mi)
    #pragma unroll
    for (int ni = 0; ni < 4; ++ni) {
      int o = (w * 4 + ni) * 16 + r16;
      #pragma unroll
      for (int r = 0; r < 4; ++r) {
        int u = mi * 16 + quad * 4 + r;
        ob[(size_t)u * 256 + o] = fmaxf(acc[mi][ni][r], 0.f);
      }
    }
}

// ---------------------------------------------------------------------------
extern "C" void kernel_launch(void* const* d_in, const int* in_sizes, int n_in,
                              void* d_out, int out_size, void* d_ws, size_t ws_size,
                              hipStream_t stream) {
  const float* feat  = (const float*)d_in[0];  // [1024, 64, 256]
  const float* adj   = (const float*)d_in[1];  // [64, 64]
  const float* W     = (const float*)d_in[2];  // [64, 256, 256]
  const float* bias  = (const float*)d_in[3];  // [64, 256]
  const float* gamma = (const float*)d_in[4];  // [64, 256]
  const float* beta  = (const float*)d_in[5];  // [64, 256]
  float* out = (float*)d_out;                  // [1024, 64, 256]

  // Ap (33.5MB) lives in d_out: unused until K4 overwrites it (stream-ordered).
  bf16_t* Ap = (bf16_t*)d_out;

  char* ws = (char*)d_ws;                      // needs ~41.3 MB
  bf16_t* Bp   = (bf16_t*)ws;                               // 8.4 MB packed W
  bf16_t* hbuf = (bf16_t*)(ws + (size_t)(9u << 20));        // 32 MB  [B][V][O] bf16
  char* tail   = ws + (size_t)(41u << 20);
  float* g_sum = (float*)tail;                              // 64 KB
  float* g_sq  = (float*)(tail + 65536);                    // 64 KB
  float* a_ws  = (float*)(tail + 2 * 65536);                // 64 KB
  float* c_ws  = (float*)(tail + 3 * 65536);                // 64 KB
  bf16_t* adjB = (bf16_t*)(tail + 4 * 65536);               //  8 KB

  hipMemsetAsync(g_sum, 0, 2 * 65536, stream);  // stats accumulators -> 0

  k0a_packW<<<513, 256, 0, stream>>>(W, adj, Bp, adjB);
  k0b_packA<<<dim3(64, 16, 2), 256, 0, stream>>>(feat, Ap);
  k1_gemm<<<dim3(64, 2, 8), 256, 0, stream>>>(Ap, Bp, bias, hbuf, g_sum, g_sq);
  k2_stats<<<64, 256, 0, stream>>>(g_sum, g_sq, gamma, beta, a_ws, c_ws);
  k4_mix<<<1024, 256, 0, stream>>>(hbuf, adjB, a_ws, c_ws, out);
}

// Round 4
// 187.481 us; speedup vs baseline: 1.2127x; 1.0078x over previous
//
#include <hip/hip_runtime.h>

// Problem constants: B=1024, V=64, DIN=256, DOUT=256, fp32 in/out.
#define EPS 1e-5f

typedef __bf16 bf16_t;
typedef bf16_t bf16x4 __attribute__((ext_vector_type(4)));
typedef bf16_t bf16x8 __attribute__((ext_vector_type(8)));
typedef float  floatx4 __attribute__((ext_vector_type(4)));

// Fragment-pack layouts (verified, rounds 1-3):
//   A-frag chunk (mt, ks, lane): A[m = mt*16 + (lane&15)][k = ks*32 + (lane>>4)*8 + j]
//   B-frag chunk (nt, ks, lane): B[k = ks*32 + (lane>>4)*8 + j][n = nt*16 + (lane&15)]
//   C/D: col = lane&15, row = (lane>>4)*4 + reg

// ---------------------------------------------------------------------------
// K0a: Bp[v][nt16][ks8][lane][8] = bf16(W[v][k][n]); bx==512: adjB = bf16(adj);
//      bx==513: zero g_sum/g_sq (replaces hipMemsetAsync -> one fewer dispatch)
// ---------------------------------------------------------------------------
__global__ __launch_bounds__(256) void k0a_packW(
    const float* __restrict__ W, const float* __restrict__ adj,
    bf16_t* __restrict__ Bp, bf16_t* __restrict__ adjB,
    float* __restrict__ g_sum, float* __restrict__ g_sq) {
  int bx = blockIdx.x, tid = threadIdx.x;
  if (bx == 513) {  // zero the stats accumulators (16384 floats each)
    float4 z = {0.f, 0.f, 0.f, 0.f};
    #pragma unroll
    for (int i = 0; i < 16; ++i) {
      *(float4*)(g_sum + (i * 256 + tid) * 4) = z;
      *(float4*)(g_sq + (i * 256 + tid) * 4) = z;
    }
    return;
  }
  if (bx == 512) {  // adjB[u*64+v] = bf16(adj[u*64+v])
    int base = tid * 16;
    #pragma unroll
    for (int half = 0; half < 2; ++half) {
      float4 f0 = *(const float4*)(adj + base + half * 8);
      float4 f1 = *(const float4*)(adj + base + half * 8 + 4);
      bf16x8 d = {(bf16_t)f0.x, (bf16_t)f0.y, (bf16_t)f0.z, (bf16_t)f0.w,
                  (bf16_t)f1.x, (bf16_t)f1.y, (bf16_t)f1.z, (bf16_t)f1.w};
      *(bf16x8*)(adjB + base + half * 8) = d;
    }
    return;
  }
  int v = bx >> 3, ks = bx & 7, k0 = ks * 32;
  __shared__ __attribute__((aligned(16))) float Ls[32][260];
  const float* Wv = W + (size_t)v * 65536;
  #pragma unroll
  for (int it = 0; it < 8; ++it) {
    int idx = it * 256 + tid;
    int row = idx >> 6, c4 = idx & 63;
    *(float4*)&Ls[row][c4 * 4] = *(const float4*)(Wv + (size_t)(k0 + row) * 256 + c4 * 4);
  }
  __syncthreads();
  #pragma unroll
  for (int it = 0; it < 4; ++it) {
    int cc = it * 256 + tid;
    int nt = cc >> 6, lanec = cc & 63;
    int n = nt * 16 + (lanec & 15), kq = (lanec >> 4) * 8;
    bf16x8 d;
    #pragma unroll
    for (int j = 0; j < 8; ++j) d[j] = (bf16_t)Ls[kq + j][n];
    *(bf16x8*)(Bp + ((size_t)(v * 16 + nt) * 8 + ks) * 512 + lanec * 8) = d;
  }
}

// ---------------------------------------------------------------------------
// K0b: Ap[v][mt64][ks8][lane][8] = bf16(feat[b = mt*16+(lane&15)][v][k])
// ---------------------------------------------------------------------------
__global__ __launch_bounds__(256) void k0b_packA(
    const float* __restrict__ feat, bf16_t* __restrict__ Ap) {
  __shared__ __attribute__((aligned(16))) float Ls[64][132];
  int tid = threadIdx.x;
  int v = blockIdx.x, bg = blockIdx.y, kh = blockIdx.z;
  const float* fp = feat + (size_t)(bg * 64) * 16384 + v * 256 + kh * 128;
  #pragma unroll
  for (int it = 0; it < 8; ++it) {
    int idx = it * 256 + tid;
    int row = idx >> 5, c4 = idx & 31;
    *(float4*)&Ls[row][c4 * 4] = *(const float4*)(fp + (size_t)row * 16384 + c4 * 4);
  }
  __syncthreads();
  #pragma unroll
  for (int it = 0; it < 4; ++it) {
    int cc = it * 256 + tid;
    int mt_l = cc >> 8, ks_l = (cc >> 6) & 3, lanec = cc & 63;
    int m_l = mt_l * 16 + (lanec & 15);
    int k_l = ks_l * 32 + (lanec >> 4) * 8;
    float4 f0 = *(const float4*)&Ls[m_l][k_l];
    float4 f1 = *(const float4*)&Ls[m_l][k_l + 4];
    bf16x8 d = {(bf16_t)f0.x, (bf16_t)f0.y, (bf16_t)f0.z, (bf16_t)f0.w,
                (bf16_t)f1.x, (bf16_t)f1.y, (bf16_t)f1.z, (bf16_t)f1.w};
    int mt = bg * 4 + mt_l, ks = kh * 4 + ks_l;
    *(bf16x8*)(Ap + ((size_t)(v * 64 + mt) * 8 + ks) * 512 + lanec * 8) = d;
  }
}

// ---------------------------------------------------------------------------
// K1: h[b,v,o] = feat@W + bias. Fragment-packed operands: all loads coalesced
//     16B/lane, zero LDS/barriers in k-loop. (r3-verified structure.)
// ---------------------------------------------------------------------------
__global__ __launch_bounds__(256, 3) void k1_gemm(
    const bf16_t* __restrict__ Ap, const bf16_t* __restrict__ Bp,
    const float* __restrict__ bias, bf16_t* __restrict__ h,
    float* __restrict__ g_sum, float* __restrict__ g_sq) {
  __shared__ __attribute__((aligned(16))) bf16_t Cs[128][136];
  __shared__ float s_sum[128], s_sq[128];

  int tid = threadIdx.x;
  int lane = tid & 63, wave = tid >> 6;
  int wm = wave >> 1, wn = wave & 1;
  int r16 = lane & 15, quad = lane >> 4;
  int v = blockIdx.x, n0 = blockIdx.y * 128, b0 = blockIdx.z * 128;

  if (tid < 128) { s_sum[tid] = 0.f; s_sq[tid] = 0.f; }

  floatx4 acc[4][4] = {};

  const bf16_t* apb[4];
  const bf16_t* bpb[4];
  #pragma unroll
  for (int mi = 0; mi < 4; ++mi) {
    int mt = blockIdx.z * 8 + wm * 4 + mi;
    apb[mi] = Ap + ((size_t)(v * 64 + mt) * 8) * 512 + lane * 8;
  }
  #pragma unroll
  for (int ni = 0; ni < 4; ++ni) {
    int nt = blockIdx.y * 8 + wn * 4 + ni;
    bpb[ni] = Bp + ((size_t)(v * 16 + nt) * 8) * 512 + lane * 8;
  }

  bf16x8 ac[4], bc[4], an[4], bn[4];
  #pragma unroll
  for (int mi = 0; mi < 4; ++mi) ac[mi] = *(const bf16x8*)apb[mi];
  #pragma unroll
  for (int ni = 0; ni < 4; ++ni) bc[ni] = *(const bf16x8*)bpb[ni];

  #pragma unroll
  for (int ks = 0; ks < 8; ++ks) {
    if (ks < 7) {
      #pragma unroll
      for (int mi = 0; mi < 4; ++mi) an[mi] = *(const bf16x8*)(apb[mi] + (ks + 1) * 512);
      #pragma unroll
      for (int ni = 0; ni < 4; ++ni) bn[ni] = *(const bf16x8*)(bpb[ni] + (ks + 1) * 512);
    }
    #pragma unroll
    for (int mi = 0; mi < 4; ++mi)
      #pragma unroll
      for (int ni = 0; ni < 4; ++ni)
        acc[mi][ni] = __builtin_amdgcn_mfma_f32_16x16x32_bf16(
            ac[mi], bc[ni], acc[mi][ni], 0, 0, 0);
    if (ks < 7) {
      #pragma unroll
      for (int mi = 0; mi < 4; ++mi) ac[mi] = an[mi];
      #pragma unroll
      for (int ni = 0; ni < 4; ++ni) bc[ni] = bn[ni];
    }
  }

  __syncthreads();

  float bias_r[4];
  #pragma unroll
  for (int ni = 0; ni < 4; ++ni)
    bias_r[ni] = bias[v * 256 + n0 + wn * 64 + ni * 16 + r16];

  #pragma unroll
  for (int ni = 0; ni < 4; ++ni) {
    int ncol = wn * 64 + ni * 16 + r16;
    float psum = 0.f, psq = 0.f;
    #pragma unroll
    for (int mi = 0; mi < 4; ++mi) {
      #pragma unroll
      for (int r = 0; r < 4; ++r) {
        int mrow = wm * 64 + mi * 16 + quad * 4 + r;
        float val = acc[mi][ni][r] + bias_r[ni];
        bf16_t hbv = (bf16_t)val;
        Cs[mrow][ncol] = hbv;
        float hf = (float)hbv;  // stats from STORED value (self-consistent BN)
        psum += hf; psq += hf * hf;
      }
    }
    atomicAdd(&s_sum[ncol], psum);
    atomicAdd(&s_sq[ncol], psq);
  }
  __syncthreads();

  bf16_t* hp = h + (size_t)v * 256 + n0;
  int col0 = (tid & 15) * 8;
  #pragma unroll
  for (int it = 0; it < 8; ++it) {
    int row = it * 16 + (tid >> 4);
    *(bf16x8*)(hp + (size_t)(b0 + row) * 16384 + col0) = *(const bf16x8*)&Cs[row][col0];
  }
  if (tid < 128) {
    atomicAdd(&g_sum[v * 256 + n0 + tid], s_sum[tid]);
    atomicAdd(&g_sq[v * 256 + n0 + tid], s_sq[tid]);
  }
}

// ---------------------------------------------------------------------------
// K2: fold BN into per-(v,o) affine, emitted as BF16 (halves k4 param traffic)
// ---------------------------------------------------------------------------
__global__ __launch_bounds__(256) void k2_stats(
    const float* __restrict__ g_sum, const float* __restrict__ g_sq,
    const float* __restrict__ gamma, const float* __restrict__ beta,
    bf16_t* __restrict__ a_bf, bf16_t* __restrict__ c_bf) {
  int idx = blockIdx.x * 256 + threadIdx.x;
  float s = g_sum[idx], q = g_sq[idx];
  float mean = s * (1.0f / 1024.0f);
  float var = fmaxf(q * (1.0f / 1024.0f) - mean * mean, 0.f);
  float rs = rsqrtf(var + EPS);
  float a = gamma[idx] * rs;
  a_bf[idx] = (bf16_t)a;
  c_bf[idx] = (bf16_t)(beta[idx] - mean * a);
}

// ---------------------------------------------------------------------------
// K4: out[b,u,o] = relu(sum_v adj[u,v] * (a*h+c)[b,v,o]) via bf16 MFMA.
//     One block per b. Stage hbn transposed in LDS (v-rotation swizzle), mix
//     with MFMA (A=adjB L1-hot), then re-stage out through LDS (reusing hsT)
//     for FULL-LINE dwordx4 stores (r3 used 64 scalar dword stores/thread).
// ---------------------------------------------------------------------------
__global__ __launch_bounds__(256) void k4_mix(
    const bf16_t* __restrict__ h, const bf16_t* __restrict__ adjB,
    const bf16_t* __restrict__ a_bf, const bf16_t* __restrict__ c_bf,
    float* __restrict__ out) {
  __shared__ unsigned int hsT[256 * 33];  // 33792B; reused as f32 [32][260] later
  int tid = threadIdx.x;
  int lane = tid & 63, w = tid >> 6;
  int r16 = lane & 15, quad = lane >> 4;
  int b = blockIdx.x;
  const bf16_t* hb = h + (size_t)b * 16384;

  // A-fragments (adjB 8KB, L1-hot): frag (mi, ks): u=mi*16+r16, k=ks*32+quad*8
  bf16x8 afr[4][2];
  #pragma unroll
  for (int mi = 0; mi < 4; ++mi)
    #pragma unroll
    for (int ks = 0; ks < 2; ++ks)
      afr[mi][ks] = *(const bf16x8*)(adjB + (mi * 16 + r16) * 64 + ks * 32 + quad * 8);

  // stage hbn^T: hsT[o][v'] with v rotated by (o&56) (breaks 8-way wr conflicts)
  #pragma unroll
  for (int i = 0; i < 4; ++i) {
    int idx2 = i * 256 + tid;
    int o8 = (idx2 & 31) * 8;
    int v0 = (idx2 >> 5) * 2;
    bf16x8 h0 = *(const bf16x8*)(hb + (size_t)v0 * 256 + o8);
    bf16x8 h1 = *(const bf16x8*)(hb + (size_t)(v0 + 1) * 256 + o8);
    bf16x8 a0 = *(const bf16x8*)(a_bf + v0 * 256 + o8);
    bf16x8 a1 = *(const bf16x8*)(a_bf + (v0 + 1) * 256 + o8);
    bf16x8 c0 = *(const bf16x8*)(c_bf + v0 * 256 + o8);
    bf16x8 c1 = *(const bf16x8*)(c_bf + (v0 + 1) * 256 + o8);
    #pragma unroll
    for (int j = 0; j < 8; ++j) {
      int o = o8 + j;
      unsigned short lo, hi;
      bf16_t d0 = (bf16_t)fmaf((float)h0[j], (float)a0[j], (float)c0[j]);
      bf16_t d1 = (bf16_t)fmaf((float)h1[j], (float)a1[j], (float)c1[j]);
      __builtin_memcpy(&lo, &d0, 2);
      __builtin_memcpy(&hi, &d1, 2);
      int vr = (v0 + (o & 56)) & 63;
      hsT[o * 33 + (vr >> 1)] = (unsigned int)lo | ((unsigned int)hi << 16);
    }
  }
  __syncthreads();

  // mix: wave w -> o-range w*64..+64 (nt=w*4+ni), all 4 u-tiles, 2 ksteps
  floatx4 acc[4][4] = {};
  #pragma unroll
  for (int ks = 0; ks < 2; ++ks) {
    bf16x8 bfr[4];
    #pragma unroll
    for (int ni = 0; ni < 4; ++ni) {
      int o = (w * 4 + ni) * 16 + r16;
      int vbase = ks * 32 + quad * 8;
      int vr = (vbase + (o & 56)) & 63;
      const unsigned int* src = &hsT[o * 33 + (vr >> 1)];
      unsigned int tmp[4] = {src[0], src[1], src[2], src[3]};
      __builtin_memcpy(&bfr[ni], tmp, 16);
    }
    #pragma unroll
    for (int mi = 0; mi < 4; ++mi)
      #pragma unroll
      for (int ni = 0; ni < 4; ++ni)
        acc[mi][ni] = __builtin_amdgcn_mfma_f32_16x16x32_bf16(
            afr[mi][ks], bfr[ni], acc[mi][ni], 0, 0, 0);
  }

  // epilogue: relu into LDS f32 tile (u-halves), then full-line dwordx4 stores
  float* Lf = (float*)hsT;  // [32][260] = 33280B fits in hsT
  float* ob = out + (size_t)b * 16384;
  #pragma unroll
  for (int half = 0; half < 2; ++half) {
    __syncthreads();  // previous use of hsT/Lf complete
    #pragma unroll
    for (int mi2 = 0; mi2 < 2; ++mi2) {
      int mi = half * 2 + mi2;
      #pragma unroll
      for (int ni = 0; ni < 4; ++ni) {
        int o = (w * 4 + ni) * 16 + r16;
        #pragma unroll
        for (int r = 0; r < 4; ++r) {
          int ul = mi2 * 16 + quad * 4 + r;  // u-local 0..31
          Lf[ul * 260 + o] = fmaxf(acc[mi][ni][r], 0.f);
        }
      }
    }
    __syncthreads();
    // 32 rows x 256 o fp32 -> one full 1KB row per wave-instr
    #pragma unroll
    for (int it = 0; it < 8; ++it) {
      int cid = it * 256 + tid;
      int row = cid >> 6, c4 = cid & 63;
      float4 val = *(const float4*)&Lf[row * 260 + c4 * 4];
      *(float4*)(ob + (size_t)(half * 32 + row) * 256 + c4 * 4) = val;
    }
  }
}

// ---------------------------------------------------------------------------
extern "C" void kernel_launch(void* const* d_in, const int* in_sizes, int n_in,
                              void* d_out, int out_size, void* d_ws, size_t ws_size,
                              hipStream_t stream) {
  const float* feat  = (const float*)d_in[0];  // [1024, 64, 256]
  const float* adj   = (const float*)d_in[1];  // [64, 64]
  const float* W     = (const float*)d_in[2];  // [64, 256, 256]
  const float* bias  = (const float*)d_in[3];  // [64, 256]
  const float* gamma = (const float*)d_in[4];  // [64, 256]
  const float* beta  = (const float*)d_in[5];  // [64, 256]
  float* out = (float*)d_out;                  // [1024, 64, 256]

  // Ap (33.5MB) lives in d_out: unused until K4 overwrites it (stream-ordered).
  bf16_t* Ap = (bf16_t*)d_out;

  char* ws = (char*)d_ws;                      // needs ~41.3 MB
  bf16_t* Bp   = (bf16_t*)ws;                               // 8.4 MB packed W
  bf16_t* hbuf = (bf16_t*)(ws + (size_t)(9u << 20));        // 32 MB [B][V][O] bf16
  char* tail   = ws + (size_t)(41u << 20);
  float* g_sum = (float*)tail;                              // 64 KB
  float* g_sq  = (float*)(tail + 65536);                    // 64 KB
  bf16_t* a_bf = (bf16_t*)(tail + 2 * 65536);               // 32 KB
  bf16_t* c_bf = (bf16_t*)(tail + 2 * 65536 + 32768);       // 32 KB
  bf16_t* adjB = (bf16_t*)(tail + 3 * 65536);               //  8 KB

  k0a_packW<<<514, 256, 0, stream>>>(W, adj, Bp, adjB, g_sum, g_sq);
  k0b_packA<<<dim3(64, 16, 2), 256, 0, stream>>>(feat, Ap);
  k1_gemm<<<dim3(64, 2, 8), 256, 0, stream>>>(Ap, Bp, bias, hbuf, g_sum, g_sq);
  k2_stats<<<64, 256, 0, stream>>>(g_sum, g_sq, gamma, beta, a_bf, c_bf);
  k4_mix<<<1024, 256, 0, stream>>>(hbuf, adjB, a_bf, c_bf, out);
}